// Round 10
// baseline (316.398 us; speedup 1.0000x reference)
//
#include <hip/hip_runtime.h>
#include <cstdint>
#include <cstddef>

#define BQ    4
#define NTOK  8192
#define CDIM  512
#define MDIM  128
#define NA    4096
#define RSEL  2048
#define NKEEP (NTOK - RSEL)   // 6144
#define RESCUE_CAP 2048
#define GAP_DELTA 2e-4f
#define WIN_TAU   2e-4f
#define CSPL  16

typedef float f32x4 __attribute__((ext_vector_type(4)));
typedef short short8 __attribute__((ext_vector_type(8)));

static __device__ __forceinline__ unsigned short bf16rne(float f) {
  unsigned u = __float_as_uint(f);
  return (unsigned short)((u + 0x7FFFu + ((u >> 16) & 1)) >> 16);
}

// ---------------------------------------------------------------------------
// rank_select_4096 (validated round-8, unchanged)
// ---------------------------------------------------------------------------
__device__ __forceinline__ unsigned long long rank_select_4096(
    const unsigned long long* keysL, unsigned* histL,
    unsigned long long* candL, unsigned* scanL, unsigned* shw /*[4]*/,
    int rank, int t) {
  unsigned long long pval = 0ull, pmask = 0ull;
  int curRank = rank;
  for (int lvl = 0; lvl < 3; ++lvl) {
    const int shift = 52 - lvl * 12;
#pragma unroll
    for (int i = 0; i < 4; ++i) histL[t + i * 1024] = 0;
    __syncthreads();
#pragma unroll
    for (int i = 0; i < 4; ++i) {
      unsigned long long k = keysL[t + i * 1024];
      if ((k & pmask) == pval)
        atomicAdd(&histL[(unsigned)((k >> shift) & 0xFFFull)], 1u);
    }
    __syncthreads();
    unsigned s = histL[4 * t] + histL[4 * t + 1] + histL[4 * t + 2] + histL[4 * t + 3];
    scanL[t] = s;
    __syncthreads();
    for (int off = 1; off < 1024; off <<= 1) {
      unsigned v = (t >= off) ? scanL[t - off] : 0;
      __syncthreads();
      scanL[t] += v;
      __syncthreads();
    }
    const unsigned incl = scanL[t], excl = incl - s;
    if ((int)excl <= curRank && curRank < (int)incl) {
      int r = curRank - (int)excl;
      unsigned b = 4 * t;
#pragma unroll
      for (int q = 0; q < 4; ++q) {
        unsigned c = histL[4 * t + q];
        if (r < (int)c) { b = 4 * t + q; break; }
        r -= (int)c;
      }
      shw[0] = b; shw[1] = (unsigned)r; shw[3] = histL[b];
    }
    __syncthreads();
    const unsigned bucket = shw[0];
    curRank = (int)shw[1];
    const unsigned cntB = shw[3];
    pval |= ((unsigned long long)bucket) << shift;
    pmask |= 0xFFFull << shift;
    if (cntB <= 1024u) break;
  }
  if (t == 0) shw[2] = 0;
  __syncthreads();
#pragma unroll
  for (int i = 0; i < 4; ++i) {
    unsigned long long k = keysL[t + i * 1024];
    if ((k & pmask) == pval) {
      unsigned pos = atomicAdd(&shw[2], 1u);
      if (pos < 1024u) candL[pos] = k;
    }
  }
  __syncthreads();
  const int c1 = (int)shw[2];
  int P = 64;
  while (P < c1) P <<= 1;
  for (int p = t; p < P; p += 1024)
    if (p >= c1) candL[p] = ~0ull;
  __syncthreads();
  for (int k2 = 2; k2 <= P; k2 <<= 1)
    for (int j = k2 >> 1; j > 0; j >>= 1) {
      for (int p = t; p < P; p += 1024) {
        int q = p ^ j;
        if (q > p) {
          bool up = ((p & k2) == 0);
          unsigned long long a = candL[p], c = candL[q];
          if ((a > c) == up) { candL[p] = c; candL[q] = a; }
        }
      }
      __syncthreads();
    }
  return candL[curRank];
}

// ---------------------------------------------------------------------------
// K1: metric (REVERTED to validated round-8 v4, 89 us: 128 thr, 8x8 micro,
// A+B both in LDS dbuf via global_load_lds w/ pre-swizzled source).
// ---------------------------------------------------------------------------
__global__ __launch_bounds__(128) void k_metric(const float* __restrict__ X,
                                                const float* __restrict__ W,
                                                const float* __restrict__ bias,
                                                float* __restrict__ ma,
                                                float* __restrict__ mb,
                                                unsigned short* __restrict__ maH,
                                                unsigned short* __restrict__ maM,
                                                unsigned short* __restrict__ mbH,
                                                unsigned short* __restrict__ mbM) {
  __shared__ float ldsA[2][64 * 32];
  __shared__ float ldsB[2][128 * 32];
  __shared__ float snorm[64 * 16];
  __shared__ float sinv[64];
  const int t = threadIdx.x;
  const int tok0 = blockIdx.x * 64;
  const int r8 = t & 7, cg = t >> 3;

  float acc[8][8];
#pragma unroll
  for (int i = 0; i < 8; ++i)
#pragma unroll
    for (int j = 0; j < 8; ++j) acc[i][j] = 0.f;

  const char* aSrc[4];
  const char* bSrc[8];
#pragma unroll
  for (int i = 0; i < 4; ++i) {
    int s = i * 128 + t, row = s >> 3, gr = s & 7;
    aSrc[i] = (const char*)(X + (size_t)(tok0 + row) * CDIM) + ((gr ^ (row & 7)) << 4);
  }
#pragma unroll
  for (int i = 0; i < 8; ++i) {
    int s = i * 128 + t, row = s >> 3, gr = s & 7;
    bSrc[i] = (const char*)(W + (size_t)row * CDIM) + ((gr ^ ((row >> 3) & 7)) << 4);
  }

  auto stage = [&](int bufn, int kc) {
    const size_t off = (size_t)kc << 7;
    char* da = (char*)&ldsA[bufn][0] + t * 16;
    char* db = (char*)&ldsB[bufn][0] + t * 16;
#pragma unroll
    for (int i = 0; i < 4; ++i)
      __builtin_amdgcn_global_load_lds(
          (const __attribute__((address_space(1))) void*)(aSrc[i] + off),
          (__attribute__((address_space(3))) void*)(da + i * 2048), 16, 0, 0);
#pragma unroll
    for (int i = 0; i < 8; ++i)
      __builtin_amdgcn_global_load_lds(
          (const __attribute__((address_space(1))) void*)(bSrc[i] + off),
          (__attribute__((address_space(3))) void*)(db + i * 2048), 16, 0, 0);
  };

  auto compute = [&](int bufn) {
#pragma unroll
    for (int kq = 0; kq < 8; ++kq) {
      const int gA = (kq ^ r8) << 2;
      const int gB = (kq ^ (cg & 7)) << 2;
      float4 av[8], bv[8];
#pragma unroll
      for (int i = 0; i < 8; ++i)
        av[i] = *(const float4*)&ldsA[bufn][(r8 + (i << 3)) * 32 + gA];
#pragma unroll
      for (int j = 0; j < 8; ++j)
        bv[j] = *(const float4*)&ldsB[bufn][((cg << 3) + j) * 32 + gB];
#pragma unroll
      for (int i = 0; i < 8; ++i)
#pragma unroll
        for (int j = 0; j < 8; ++j) {
          acc[i][j] = fmaf(av[i].x, bv[j].x, acc[i][j]);
          acc[i][j] = fmaf(av[i].y, bv[j].y, acc[i][j]);
          acc[i][j] = fmaf(av[i].z, bv[j].z, acc[i][j]);
          acc[i][j] = fmaf(av[i].w, bv[j].w, acc[i][j]);
        }
    }
  };

  stage(0, 0);
  __syncthreads();
  for (int kc = 0; kc < 16; ++kc) {
    if (kc + 1 < 16) stage((kc + 1) & 1, kc + 1);
    compute(kc & 1);
    __syncthreads();
  }

  float bb[8];
#pragma unroll
  for (int j = 0; j < 8; ++j) bb[j] = bias[(cg << 3) + j];
#pragma unroll
  for (int i = 0; i < 8; ++i) {
    float s = 0.f;
#pragma unroll
    for (int j = 0; j < 8; ++j) {
      acc[i][j] += bb[j];
      s = fmaf(acc[i][j], acc[i][j], s);
    }
    snorm[(r8 + (i << 3)) * 16 + cg] = s;
  }
  __syncthreads();
  if (t < 64) {
    float s = 0.f;
    for (int q = 0; q < 16; ++q) s += snorm[t * 16 + q];
    sinv[t] = 1.0f / sqrtf(s);
  }
  __syncthreads();
#pragma unroll
  for (int i = 0; i < 8; ++i) {
    int r = r8 + (i << 3);
    int tokg = tok0 + r;
    float inv = sinv[r];
    int bq = tokg >> 13, pos = tokg & (NTOK - 1);
    size_t eidx = ((size_t)bq * NA + (pos >> 1)) * MDIM + (cg << 3);
    float vv[8];
#pragma unroll
    for (int j = 0; j < 8; ++j) vv[j] = acc[i][j] * inv;
    float* dst = ((pos & 1) ? mb : ma) + eidx;
    *(float4*)dst = make_float4(vv[0], vv[1], vv[2], vv[3]);
    *(float4*)(dst + 4) = make_float4(vv[4], vv[5], vv[6], vv[7]);
    unsigned hB[8], mB[8];
#pragma unroll
    for (int j = 0; j < 8; ++j) {
      hB[j] = bf16rne(vv[j]);
      mB[j] = bf16rne(vv[j] - __uint_as_float(hB[j] << 16));
    }
    uint4 hw, mw;
    hw.x = hB[0] | (hB[1] << 16); hw.y = hB[2] | (hB[3] << 16);
    hw.z = hB[4] | (hB[5] << 16); hw.w = hB[6] | (hB[7] << 16);
    mw.x = mB[0] | (mB[1] << 16); mw.y = mB[2] | (mB[3] << 16);
    mw.z = mB[4] | (mB[5] << 16); mw.w = mB[6] | (mB[7] << 16);
    *(uint4*)(((pos & 1) ? mbH : maH) + eidx) = hw;
    *(uint4*)(((pos & 1) ? mbM : maM) + eidx) = mw;
  }
}

// ---------------------------------------------------------------------------
// K2 v3: scores via split-bf16 MFMA. 32 a-rows/wave (1:3 LDS:MFMA ratio,
// round-5 layout) + 16-c chunks (16 KB LDS, 12 waves/CU) -> MFMA-bound.
// grid = 4 bq x 32 at(128 rows) x 16 cs(256 c) = 2048 blocks.
// ---------------------------------------------------------------------------
__global__ __launch_bounds__(256, 3) void k_scores_mfma(
    const unsigned short* __restrict__ maH, const unsigned short* __restrict__ maM,
    const unsigned short* __restrict__ mbH, const unsigned short* __restrict__ mbM,
    float* __restrict__ pv1, int* __restrict__ pi1, float* __restrict__ pv2) {
  __shared__ short8 lds8[2][2][16][16];   // [buf][plane][c][granule], 16 KB
  const int t = threadIdx.x;
  const int bid = blockIdx.x;
  const int bq = bid >> 9, rem = bid & 511, at = rem >> 4, cs = rem & 15;
  const int a0 = at * 128;
  const int l = t & 63, w = t >> 6;
  const int l15 = l & 15, l4 = l >> 4;

  // A fragments: 32 rows/wave (rf 0,1), K=128 in 4 chunks, hi+mid (64 VGPR).
  short8 aH[2][4], aM[2][4];
#pragma unroll
  for (int rf = 0; rf < 2; ++rf)
#pragma unroll
    for (int kc = 0; kc < 4; ++kc) {
      size_t aidx = ((size_t)bq * NA + a0 + w * 32 + rf * 16 + l15) * MDIM
                    + kc * 32 + l4 * 8;
      aH[rf][kc] = *(const short8*)(maH + aidx);
      aM[rf][kc] = *(const short8*)(maM + aidx);
    }

  // staging: 2 issues/thread (plane = issue); src pre-swizzled (g ^= c&7)
  const int scl = t >> 4, sg = t & 15;
  const size_t srow = ((size_t)bq * NA + cs * 256 + scl) << 8;
  const size_t soff = srow + (size_t)((sg ^ (scl & 7)) << 4);
  const char* spH = (const char*)mbH + soff;
  const char* spM = (const char*)mbM + soff;

  auto stage = [&](int bufn) {
    char* dst = (char*)&lds8[bufn][0][0][0] + t * 16;
    __builtin_amdgcn_global_load_lds(
        (const __attribute__((address_space(1))) void*)spH,
        (__attribute__((address_space(3))) void*)dst, 16, 0, 0);
    __builtin_amdgcn_global_load_lds(
        (const __attribute__((address_space(1))) void*)spM,
        (__attribute__((address_space(3))) void*)(dst + 4096), 16, 0, 0);
    spH += 4096; spM += 4096;     // next chunk: +16 c rows x 256 B
  };

  float bv1[8], bv2[8];
  int bi1[8];
#pragma unroll
  for (int s = 0; s < 8; ++s) { bv1[s] = -1e30f; bv2[s] = -1e30f; bi1[s] = 0x7FFFFFFF; }

  auto compute = [&](int bufn, int cbase) {
    f32x4 acc1[2], acc2[2];
    acc1[0] = 0.f; acc1[1] = 0.f; acc2[0] = 0.f; acc2[1] = 0.f;
#pragma unroll
    for (int kc = 0; kc < 4; ++kc) {
      const int gg = (kc * 4 + l4) ^ (l15 & 7);
      short8 bh = lds8[bufn][0][l15][gg];
      short8 bm = lds8[bufn][1][l15][gg];
#pragma unroll
      for (int rf = 0; rf < 2; ++rf) {
        acc1[rf] = __builtin_amdgcn_mfma_f32_16x16x32_bf16(aH[rf][kc], bh, acc1[rf], 0, 0, 0);
        acc2[rf] = __builtin_amdgcn_mfma_f32_16x16x32_bf16(aH[rf][kc], bm, acc2[rf], 0, 0, 0);
        acc2[rf] = __builtin_amdgcn_mfma_f32_16x16x32_bf16(aM[rf][kc], bh, acc2[rf], 0, 0, 0);
      }
    }
    const int cg = cbase + l15;
#pragma unroll
    for (int rf = 0; rf < 2; ++rf) {
      f32x4 v4 = acc1[rf] + acc2[rf];
#pragma unroll
      for (int r2 = 0; r2 < 4; ++r2) {
        float v = v4[r2];
        int s = rf * 4 + r2;
        if (v > bv1[s]) { bv2[s] = bv1[s]; bv1[s] = v; bi1[s] = cg; }
        else if (v > bv2[s]) bv2[s] = v;
      }
    }
  };

  stage(0);
  __syncthreads();
  const int cb0 = cs * 256;
  for (int chp = 0; chp < 8; ++chp) {   // 16 chunks of 16 c, 2 per iteration
    const int ch = chp * 2;
    if (ch + 1 < 16) stage(1);
    compute(0, cb0 + ch * 16);
    __syncthreads();
    if (ch + 2 < 16) stage(0);
    compute(1, cb0 + ch * 16 + 16);
    __syncthreads();
  }

  // cross-lane top-2 reduce over the 16 c-lanes sharing each row (round-5)
#pragma unroll
  for (int s = 0; s < 8; ++s) {
    float v1 = bv1[s], v2 = bv2[s];
    int i1 = bi1[s];
#pragma unroll
    for (int m = 1; m < 16; m <<= 1) {
      float V1 = __shfl_xor(v1, m);
      int I1 = __shfl_xor(i1, m);
      float V2 = __shfl_xor(v2, m);
      bool take = (V1 > v1) || (V1 == v1 && I1 < i1);
      float lose = take ? v1 : V1;
      if (take) { v1 = V1; i1 = I1; }
      v2 = fmaxf(fmaxf(v2, V2), lose);
    }
    if (l15 == s) {
      int row = a0 + w * 32 + (s >> 2) * 16 + (l4 << 2) + (s & 3);
      size_t off = ((size_t)(bq * CSPL + cs)) * NA + row;
      pv1[off] = v1; pi1[off] = i1; pv2[off] = v2;
    }
  }
}

// ---------------------------------------------------------------------------
// K3 (fused): merge CSPL csplit partials + init + rank-select vb + mark.
// ---------------------------------------------------------------------------
__global__ __launch_bounds__(1024) void k_mergemark(
    const float* __restrict__ pv1, const int* __restrict__ pi1,
    const float* __restrict__ pv2,
    float* __restrict__ valA, int* __restrict__ nodeA,
    int* __restrict__ rescueCnt, int* __restrict__ rescueIdx,
    int* __restrict__ cnt, int* __restrict__ head,
    unsigned long long* __restrict__ rescueKey) {
  __shared__ unsigned long long keys[NA];
  __shared__ unsigned hist[NA];
  __shared__ unsigned long long cand[1024];
  __shared__ unsigned scan1[1024];
  __shared__ unsigned shw[4];
  const int b = blockIdx.x, t = threadIdx.x;
  if (t == 0) rescueCnt[b] = 0;
  float gval[4], ggap[4];
#pragma unroll
  for (int k4 = 0; k4 < 4; ++k4) {
    const int p = t + k4 * 1024;
    const size_t i = (size_t)b * NA + p;
    float v1 = -1e30f, v2 = -1e30f;
    int i1 = 0x7FFFFFFF;
#pragma unroll
    for (int cspl = 0; cspl < CSPL; ++cspl) {
      size_t o = ((size_t)(b * CSPL + cspl)) * NA + p;
      float V1 = pv1[o], V2 = pv2[o];
      int I1 = pi1[o];
      bool take = (V1 > v1) || (V1 == v1 && I1 < i1);
      float lose = take ? v1 : V1;
      if (take) { v1 = V1; i1 = I1; }
      v2 = fmaxf(fmaxf(v2, V2), lose);
    }
    valA[i] = v1; nodeA[i] = i1;
    cnt[i] = 0; head[i] = -1; rescueKey[i] = 0ull;
    gval[k4] = v1; ggap[k4] = v1 - v2;
    unsigned u = __float_as_uint(v1);
    unsigned mono = u ^ ((u >> 31) ? 0xFFFFFFFFu : 0x80000000u);
    keys[p] = ((unsigned long long)(~mono) << 32) | (unsigned)p;
  }
  __syncthreads();

  const unsigned long long thr =
      rank_select_4096(keys, hist, cand, scan1, shw, RSEL - 1, t);
  unsigned monoT = ~(unsigned)(thr >> 32);
  unsigned uT = (monoT >> 31) ? (monoT ^ 0x80000000u) : ~monoT;
  const float vb = __uint_as_float(uT);

#pragma unroll
  for (int k4 = 0; k4 < 4; ++k4) {
    const int p = t + k4 * 1024;
    if (ggap[k4] < GAP_DELTA || fabsf(gval[k4] - vb) <= WIN_TAU) {
      int slot = atomicAdd(&rescueCnt[b], 1);
      if (slot < RESCUE_CAP) rescueIdx[b * RESCUE_CAP + slot] = p;
    }
  }
}

// ---------------------------------------------------------------------------
// K4: exact fp32 recompute, parallel over (slot x 16 column-chunks).
// (validated, unchanged)
// ---------------------------------------------------------------------------
__global__ __launch_bounds__(256) void k_rescue(const float* __restrict__ ma,
                                                const float* __restrict__ mb,
                                                const int* __restrict__ rescueIdx,
                                                const int* __restrict__ rescueCnt,
                                                unsigned long long* __restrict__ key) {
  const int bq = blockIdx.x >> 8;
  const int wid = blockIdx.x & 255;
  const int cnt = min(rescueCnt[bq], RESCUE_CAP);
  const int npair = cnt * 16;
  const int t = threadIdx.x;
  __shared__ float sA[128];
  __shared__ float wv[4];
  __shared__ int   wi[4];
  for (int pair = wid; pair < npair; pair += 256) {
    const int slot = pair >> 4, chunk = pair & 15;
    const int row = rescueIdx[bq * RESCUE_CAP + slot];
    __syncthreads();
    if (t < 128) sA[t] = ma[((size_t)bq * NA + row) * MDIM + t];
    __syncthreads();
    const int c = chunk * 256 + t;
    const float* bp = mb + ((size_t)bq * NA + c) * MDIM;
    float d0 = 0.f, d1 = 0.f, d2 = 0.f, d3 = 0.f;
#pragma unroll
    for (int j = 0; j < 8; ++j) {
      float4 b0 = *(const float4*)(bp + j * 16 + 0);
      float4 b1 = *(const float4*)(bp + j * 16 + 4);
      float4 b2 = *(const float4*)(bp + j * 16 + 8);
      float4 b3 = *(const float4*)(bp + j * 16 + 12);
      const float4 a0 = *(const float4*)&sA[j * 16 + 0];
      const float4 a1 = *(const float4*)&sA[j * 16 + 4];
      const float4 a2 = *(const float4*)&sA[j * 16 + 8];
      const float4 a3 = *(const float4*)&sA[j * 16 + 12];
      d0 = fmaf(a0.x, b0.x, d0); d0 = fmaf(a0.y, b0.y, d0);
      d0 = fmaf(a0.z, b0.z, d0); d0 = fmaf(a0.w, b0.w, d0);
      d1 = fmaf(a1.x, b1.x, d1); d1 = fmaf(a1.y, b1.y, d1);
      d1 = fmaf(a1.z, b1.z, d1); d1 = fmaf(a1.w, b1.w, d1);
      d2 = fmaf(a2.x, b2.x, d2); d2 = fmaf(a2.y, b2.y, d2);
      d2 = fmaf(a2.z, b2.z, d2); d2 = fmaf(a2.w, b2.w, d2);
      d3 = fmaf(a3.x, b3.x, d3); d3 = fmaf(a3.y, b3.y, d3);
      d3 = fmaf(a3.z, b3.z, d3); d3 = fmaf(a3.w, b3.w, d3);
    }
    float d = (d0 + d1) + (d2 + d3);
    int ci = c;
#pragma unroll
    for (int m = 1; m < 64; m <<= 1) {
      float V = __shfl_xor(d, m);
      int C = __shfl_xor(ci, m);
      if (V > d || (V == d && C < ci)) { d = V; ci = C; }
    }
    if ((t & 63) == 0) { wv[t >> 6] = d; wi[t >> 6] = ci; }
    __syncthreads();
    if (t == 0) {
      for (int w2 = 1; w2 < 4; ++w2)
        if (wv[w2] > d || (wv[w2] == d && wi[w2] < ci)) { d = wv[w2]; ci = wi[w2]; }
      unsigned u = __float_as_uint(d);
      unsigned mono = u ^ ((u >> 31) ? 0xFFFFFFFFu : 0x80000000u);
      unsigned long long k = ((unsigned long long)mono << 32)
                           | (unsigned)(0xFFFFFFFFu - (unsigned)ci);
      atomicMax(&key[(size_t)bq * NA + row], k);
    }
  }
}

// ---------------------------------------------------------------------------
// K5 (fused): decode rescued keys + exact top-2048 via rank-select + build
// merge lists + mask scan -> newidx + ownership. (validated, unchanged)
// ---------------------------------------------------------------------------
__global__ __launch_bounds__(1024) void k_select(
    const unsigned long long* __restrict__ rescueKey,
    const float* __restrict__ valA, const int* __restrict__ nodeA,
    int* __restrict__ sel, int* __restrict__ cnt, int* __restrict__ head,
    int* __restrict__ nxt, int* __restrict__ newidx,
    float* __restrict__ own) {
  __shared__ unsigned long long keys[NA];
  __shared__ int nodeL[NA];
  __shared__ unsigned char selL[NA];
  __shared__ int ni[NTOK];
  __shared__ unsigned tot[1024];
  __shared__ unsigned hist[NA];
  __shared__ unsigned long long cand[1024];
  __shared__ unsigned shw[4];
  const int b = blockIdx.x, t = threadIdx.x;

#pragma unroll
  for (int k4 = 0; k4 < 4; ++k4) {
    const int p = t + k4 * 1024;
    const size_t i = (size_t)b * NA + p;
    unsigned long long rk = rescueKey[i];
    float v; int nd;
    if (rk) {
      unsigned mono = (unsigned)(rk >> 32);
      unsigned u = (mono & 0x80000000u) ? (mono ^ 0x80000000u) : ~mono;
      v = __uint_as_float(u);
      nd = (int)(0xFFFFFFFFu - (unsigned)(rk & 0xFFFFFFFFull));
    } else {
      v = valA[i];
      nd = nodeA[i];
    }
    nodeL[p] = nd;
    unsigned u = __float_as_uint(v);
    unsigned mono = u ^ ((u >> 31) ? 0xFFFFFFFFu : 0x80000000u);
    keys[p] = ((unsigned long long)(~mono) << 32) | (unsigned)p;
  }
  __syncthreads();

  const unsigned long long thr =
      rank_select_4096(keys, hist, cand, tot, shw, RSEL - 1, t);

#pragma unroll
  for (int k4 = 0; k4 < 4; ++k4) {
    const int p = t + k4 * 1024;
    selL[p] = (keys[p] <= thr) ? 1 : 0;
  }
  __syncthreads();

#pragma unroll
  for (int k4 = 0; k4 < 4; ++k4) {
    const int p = t + k4 * 1024;
    const size_t i = (size_t)b * NA + p;
    int s = selL[p];
    sel[i] = s;
    if (s) {
      int dst = nodeL[p];
      atomicAdd(&cnt[(size_t)b * NA + dst], 1);
      nxt[i] = atomicExch(&head[(size_t)b * NA + dst], p);
    }
  }

  const int base = t * 8;
  int kept[8], run = 0;
#pragma unroll
  for (int e = 0; e < 8; ++e) {
    int idx = base + e;
    int kp = ((idx & 1) == 0) ? 1 : (selL[idx >> 1] ? 0 : 1);
    kept[e] = kp;
    run += kp;
  }
  tot[t] = (unsigned)run;
  __syncthreads();
  for (int off = 1; off < 1024; off <<= 1) {
    unsigned v = (t >= off) ? tot[t - off] : 0;
    __syncthreads();
    tot[t] += v;
    __syncthreads();
  }
  int cum = (int)tot[t] - run;
#pragma unroll
  for (int e = 0; e < 8; ++e) {
    cum += kept[e];
    ni[base + e] = cum - 1;
  }
  __syncthreads();
#pragma unroll
  for (int e = 0; e < 8; ++e) {
    int idx = base + e;
    int ow = kept[e] ? ni[idx] : ni[2 * nodeL[idx >> 1]];
    newidx[(size_t)b * NTOK + idx] = ni[idx];
    own[(size_t)b * NTOK + idx] = (float)ow;
  }
}

// ---------------------------------------------------------------------------
// K6: assemble x_final (validated, unchanged)
// ---------------------------------------------------------------------------
__global__ __launch_bounds__(256) void k_assemble(const float* __restrict__ X,
                                                  const int* __restrict__ sel,
                                                  const int* __restrict__ newidx,
                                                  const int* __restrict__ cnt,
                                                  const int* __restrict__ head,
                                                  const int* __restrict__ nxt,
                                                  float* __restrict__ out) {
  const int token = blockIdx.x * 2 + (threadIdx.x >> 7);
  const int bq = token >> 13, tp = token & (NTOK - 1);
  const int t = threadIdx.x & 127;
  if ((tp & 1) && sel[(size_t)bq * NA + (tp >> 1)]) return;
  float4 v = *(const float4*)(X + (size_t)token * CDIM + t * 4);
  if (!(tp & 1)) {
    size_t slot = (size_t)bq * NA + (tp >> 1);
    int c = cnt[slot];
    if (c > 0) {
      int kk = head[slot];
      while (kk >= 0) {
        float4 s = *(const float4*)(X + ((size_t)bq * NTOK + 2 * kk + 1) * CDIM + t * 4);
        v.x += s.x; v.y += s.y; v.z += s.z; v.w += s.w;
        kk = nxt[(size_t)bq * NA + kk];
      }
      float inv = 1.0f / (float)(1 + c);
      v.x *= inv; v.y *= inv; v.z *= inv; v.w *= inv;
    }
  }
  int dst = newidx[(size_t)bq * NTOK + tp];
  *(float4*)(out + ((size_t)bq * NKEEP + dst) * CDIM + t * 4) = v;
}

// ---------------------------------------------------------------------------
extern "C" void kernel_launch(void* const* d_in, const int* in_sizes, int n_in,
                              void* d_out, int out_size, void* d_ws, size_t ws_size,
                              hipStream_t stream) {
  const float* X    = (const float*)d_in[0];
  const float* W    = (const float*)d_in[1];
  const float* bias = (const float*)d_in[2];
  float* out = (float*)d_out;  // f32: x_final (4,6144,512) ++ ownership (4,8192)
  char* ws = (char*)d_ws;

  size_t o = 0;
  float* ma   = (float*)(ws + o); o += (size_t)BQ * NA * MDIM * 4;
  float* mb   = (float*)(ws + o); o += (size_t)BQ * NA * MDIM * 4;
  unsigned short* maH = (unsigned short*)(ws + o); o += (size_t)BQ * NA * MDIM * 2;
  unsigned short* maM = (unsigned short*)(ws + o); o += (size_t)BQ * NA * MDIM * 2;
  unsigned short* mbH = (unsigned short*)(ws + o); o += (size_t)BQ * NA * MDIM * 2;
  unsigned short* mbM = (unsigned short*)(ws + o); o += (size_t)BQ * NA * MDIM * 2;
  float* pv1  = (float*)(ws + o); o += (size_t)BQ * CSPL * NA * 4;
  int*   pi1  = (int*)(ws + o);   o += (size_t)BQ * CSPL * NA * 4;
  float* pv2  = (float*)(ws + o); o += (size_t)BQ * CSPL * NA * 4;
  float* valA = (float*)(ws + o); o += (size_t)BQ * NA * 4;
  int*   nodeA= (int*)(ws + o);   o += (size_t)BQ * NA * 4;
  int*   sel  = (int*)(ws + o);   o += (size_t)BQ * NA * 4;
  int*   cnt  = (int*)(ws + o);   o += (size_t)BQ * NA * 4;
  int*   head = (int*)(ws + o);   o += (size_t)BQ * NA * 4;
  int*   nxt  = (int*)(ws + o);   o += (size_t)BQ * NA * 4;
  int*   newidx = (int*)(ws + o); o += (size_t)BQ * NTOK * 4;
  int*   rescueCnt = (int*)(ws + o); o += 256;
  int*   rescueIdx = (int*)(ws + o); o += (size_t)BQ * RESCUE_CAP * 4;
  unsigned long long* rescueKey = (unsigned long long*)(ws + o); o += (size_t)BQ * NA * 8;
  (void)in_sizes; (void)n_in; (void)out_size; (void)ws_size;

  k_metric<<<512, 128, 0, stream>>>(X, W, bias, ma, mb, maH, maM, mbH, mbM);
  k_scores_mfma<<<BQ * 32 * CSPL, 256, 0, stream>>>(maH, maM, mbH, mbM, pv1, pi1, pv2);
  k_mergemark<<<BQ, 1024, 0, stream>>>(pv1, pi1, pv2, valA, nodeA,
                                       rescueCnt, rescueIdx, cnt, head, rescueKey);
  k_rescue<<<BQ * 256, 256, 0, stream>>>(ma, mb, rescueIdx, rescueCnt, rescueKey);
  k_select<<<BQ, 1024, 0, stream>>>(rescueKey, valA, nodeA, sel, cnt, head, nxt,
                                    newidx, out + (size_t)BQ * NKEEP * CDIM);
  k_assemble<<<BQ * NTOK / 2, 256, 0, stream>>>(X, sel, newidx, cnt, head, nxt, out);
}

// Round 11
// 273.907 us; speedup vs baseline: 1.1551x; 1.1551x over previous
//
#include <hip/hip_runtime.h>
#include <cstdint>
#include <cstddef>

#define BQ    4
#define NTOK  8192
#define CDIM  512
#define MDIM  128
#define NA    4096
#define RSEL  2048
#define NKEEP (NTOK - RSEL)   // 6144
#define RESCUE_CAP 2048
#define GAP_DELTA 2e-4f
#define WIN_TAU   2e-4f
#define CSPL  8

typedef float f32x4 __attribute__((ext_vector_type(4)));
typedef short short8 __attribute__((ext_vector_type(8)));

static __device__ __forceinline__ unsigned short bf16rne(float f) {
  unsigned u = __float_as_uint(f);
  return (unsigned short)((u + 0x7FFFu + ((u >> 16) & 1)) >> 16);
}

// ---------------------------------------------------------------------------
// rank_select_4096: exact (rank)-th smallest (0-indexed) of 4096 UNIQUE u64
// keys resident in LDS, without sorting them. (validated round-8, unchanged)
// ---------------------------------------------------------------------------
__device__ __forceinline__ unsigned long long rank_select_4096(
    const unsigned long long* keysL, unsigned* histL,
    unsigned long long* candL, unsigned* scanL, unsigned* shw /*[4]*/,
    int rank, int t) {
  unsigned long long pval = 0ull, pmask = 0ull;
  int curRank = rank;
  for (int lvl = 0; lvl < 3; ++lvl) {
    const int shift = 52 - lvl * 12;
#pragma unroll
    for (int i = 0; i < 4; ++i) histL[t + i * 1024] = 0;
    __syncthreads();
#pragma unroll
    for (int i = 0; i < 4; ++i) {
      unsigned long long k = keysL[t + i * 1024];
      if ((k & pmask) == pval)
        atomicAdd(&histL[(unsigned)((k >> shift) & 0xFFFull)], 1u);
    }
    __syncthreads();
    unsigned s = histL[4 * t] + histL[4 * t + 1] + histL[4 * t + 2] + histL[4 * t + 3];
    scanL[t] = s;
    __syncthreads();
    for (int off = 1; off < 1024; off <<= 1) {
      unsigned v = (t >= off) ? scanL[t - off] : 0;
      __syncthreads();
      scanL[t] += v;
      __syncthreads();
    }
    const unsigned incl = scanL[t], excl = incl - s;
    if ((int)excl <= curRank && curRank < (int)incl) {
      int r = curRank - (int)excl;
      unsigned b = 4 * t;
#pragma unroll
      for (int q = 0; q < 4; ++q) {
        unsigned c = histL[4 * t + q];
        if (r < (int)c) { b = 4 * t + q; break; }
        r -= (int)c;
      }
      shw[0] = b; shw[1] = (unsigned)r; shw[3] = histL[b];
    }
    __syncthreads();
    const unsigned bucket = shw[0];
    curRank = (int)shw[1];
    const unsigned cntB = shw[3];
    pval |= ((unsigned long long)bucket) << shift;
    pmask |= 0xFFFull << shift;
    if (cntB <= 1024u) break;
  }
  if (t == 0) shw[2] = 0;
  __syncthreads();
#pragma unroll
  for (int i = 0; i < 4; ++i) {
    unsigned long long k = keysL[t + i * 1024];
    if ((k & pmask) == pval) {
      unsigned pos = atomicAdd(&shw[2], 1u);
      if (pos < 1024u) candL[pos] = k;
    }
  }
  __syncthreads();
  const int c1 = (int)shw[2];
  int P = 64;
  while (P < c1) P <<= 1;
  for (int p = t; p < P; p += 1024)
    if (p >= c1) candL[p] = ~0ull;
  __syncthreads();
  for (int k2 = 2; k2 <= P; k2 <<= 1)
    for (int j = k2 >> 1; j > 0; j >>= 1) {
      for (int p = t; p < P; p += 1024) {
        int q = p ^ j;
        if (q > p) {
          bool up = ((p & k2) == 0);
          unsigned long long a = candL[p], c = candL[q];
          if ((a > c) == up) { candL[p] = c; candL[q] = a; }
        }
      }
      __syncthreads();
    }
  return candL[curRank];
}

// ---------------------------------------------------------------------------
// K1: metric = x @ W^T + b, row-normalize, split even/odd rows into ma/mb
// (fp32) AND emit bf16 hi/mid planes. (validated round-8 v4: 128 thr, 8x8
// micro, A+B LDS dbuf via global_load_lds w/ pre-swizzled source, 89 us)
// ---------------------------------------------------------------------------
__global__ __launch_bounds__(128) void k_metric(const float* __restrict__ X,
                                                const float* __restrict__ W,
                                                const float* __restrict__ bias,
                                                float* __restrict__ ma,
                                                float* __restrict__ mb,
                                                unsigned short* __restrict__ maH,
                                                unsigned short* __restrict__ maM,
                                                unsigned short* __restrict__ mbH,
                                                unsigned short* __restrict__ mbM) {
  __shared__ float ldsA[2][64 * 32];
  __shared__ float ldsB[2][128 * 32];
  __shared__ float snorm[64 * 16];
  __shared__ float sinv[64];
  const int t = threadIdx.x;
  const int tok0 = blockIdx.x * 64;
  const int r8 = t & 7, cg = t >> 3;

  float acc[8][8];
#pragma unroll
  for (int i = 0; i < 8; ++i)
#pragma unroll
    for (int j = 0; j < 8; ++j) acc[i][j] = 0.f;

  const char* aSrc[4];
  const char* bSrc[8];
#pragma unroll
  for (int i = 0; i < 4; ++i) {
    int s = i * 128 + t, row = s >> 3, gr = s & 7;
    aSrc[i] = (const char*)(X + (size_t)(tok0 + row) * CDIM) + ((gr ^ (row & 7)) << 4);
  }
#pragma unroll
  for (int i = 0; i < 8; ++i) {
    int s = i * 128 + t, row = s >> 3, gr = s & 7;
    bSrc[i] = (const char*)(W + (size_t)row * CDIM) + ((gr ^ ((row >> 3) & 7)) << 4);
  }

  auto stage = [&](int bufn, int kc) {
    const size_t off = (size_t)kc << 7;
    char* da = (char*)&ldsA[bufn][0] + t * 16;
    char* db = (char*)&ldsB[bufn][0] + t * 16;
#pragma unroll
    for (int i = 0; i < 4; ++i)
      __builtin_amdgcn_global_load_lds(
          (const __attribute__((address_space(1))) void*)(aSrc[i] + off),
          (__attribute__((address_space(3))) void*)(da + i * 2048), 16, 0, 0);
#pragma unroll
    for (int i = 0; i < 8; ++i)
      __builtin_amdgcn_global_load_lds(
          (const __attribute__((address_space(1))) void*)(bSrc[i] + off),
          (__attribute__((address_space(3))) void*)(db + i * 2048), 16, 0, 0);
  };

  auto compute = [&](int bufn) {
#pragma unroll
    for (int kq = 0; kq < 8; ++kq) {
      const int gA = (kq ^ r8) << 2;
      const int gB = (kq ^ (cg & 7)) << 2;
      float4 av[8], bv[8];
#pragma unroll
      for (int i = 0; i < 8; ++i)
        av[i] = *(const float4*)&ldsA[bufn][(r8 + (i << 3)) * 32 + gA];
#pragma unroll
      for (int j = 0; j < 8; ++j)
        bv[j] = *(const float4*)&ldsB[bufn][((cg << 3) + j) * 32 + gB];
#pragma unroll
      for (int i = 0; i < 8; ++i)
#pragma unroll
        for (int j = 0; j < 8; ++j) {
          acc[i][j] = fmaf(av[i].x, bv[j].x, acc[i][j]);
          acc[i][j] = fmaf(av[i].y, bv[j].y, acc[i][j]);
          acc[i][j] = fmaf(av[i].z, bv[j].z, acc[i][j]);
          acc[i][j] = fmaf(av[i].w, bv[j].w, acc[i][j]);
        }
    }
  };

  stage(0, 0);
  __syncthreads();
  for (int kc = 0; kc < 16; ++kc) {
    if (kc + 1 < 16) stage((kc + 1) & 1, kc + 1);
    compute(kc & 1);
    __syncthreads();
  }

  float bb[8];
#pragma unroll
  for (int j = 0; j < 8; ++j) bb[j] = bias[(cg << 3) + j];
#pragma unroll
  for (int i = 0; i < 8; ++i) {
    float s = 0.f;
#pragma unroll
    for (int j = 0; j < 8; ++j) {
      acc[i][j] += bb[j];
      s = fmaf(acc[i][j], acc[i][j], s);
    }
    snorm[(r8 + (i << 3)) * 16 + cg] = s;
  }
  __syncthreads();
  if (t < 64) {
    float s = 0.f;
    for (int q = 0; q < 16; ++q) s += snorm[t * 16 + q];
    sinv[t] = 1.0f / sqrtf(s);
  }
  __syncthreads();
#pragma unroll
  for (int i = 0; i < 8; ++i) {
    int r = r8 + (i << 3);
    int tokg = tok0 + r;
    float inv = sinv[r];
    int bq = tokg >> 13, pos = tokg & (NTOK - 1);
    size_t eidx = ((size_t)bq * NA + (pos >> 1)) * MDIM + (cg << 3);
    float vv[8];
#pragma unroll
    for (int j = 0; j < 8; ++j) vv[j] = acc[i][j] * inv;
    float* dst = ((pos & 1) ? mb : ma) + eidx;
    *(float4*)dst = make_float4(vv[0], vv[1], vv[2], vv[3]);
    *(float4*)(dst + 4) = make_float4(vv[4], vv[5], vv[6], vv[7]);
    unsigned hB[8], mB[8];
#pragma unroll
    for (int j = 0; j < 8; ++j) {
      hB[j] = bf16rne(vv[j]);
      mB[j] = bf16rne(vv[j] - __uint_as_float(hB[j] << 16));
    }
    uint4 hw, mw;
    hw.x = hB[0] | (hB[1] << 16); hw.y = hB[2] | (hB[3] << 16);
    hw.z = hB[4] | (hB[5] << 16); hw.w = hB[6] | (hB[7] << 16);
    mw.x = mB[0] | (mB[1] << 16); mw.y = mB[2] | (mB[3] << 16);
    mw.z = mB[4] | (mB[5] << 16); mw.w = mB[6] | (mB[7] << 16);
    *(uint4*)(((pos & 1) ? mbH : maH) + eidx) = hw;
    *(uint4*)(((pos & 1) ? mbM : maM) + eidx) = mw;
  }
}

// ---------------------------------------------------------------------------
// K2: scores via split-bf16 MFMA (hi*hi + hi*mid + mid*hi), per-row top-2.
// (validated round-6/7/8 version: 16 a-rows/wave, 32-c chunks, 32 KB LDS,
// 4 blocks/CU x 4 waves)
// ---------------------------------------------------------------------------
__global__ __launch_bounds__(256, 4) void k_scores_mfma(
    const unsigned short* __restrict__ maH, const unsigned short* __restrict__ maM,
    const unsigned short* __restrict__ mbH, const unsigned short* __restrict__ mbM,
    float* __restrict__ pv1, int* __restrict__ pi1, float* __restrict__ pv2) {
  __shared__ short8 lds8[2][2][32][16];
  const int t = threadIdx.x;
  const int bid = blockIdx.x;
  const int bq = bid >> 9, rem = bid & 511, at = rem >> 3, cs = rem & 7;
  const int a0 = at * 64;
  const int l = t & 63, w = t >> 6;
  const int l15 = l & 15, l4 = l >> 4, l7 = l & 7;

  short8 aH[4], aM[4];
#pragma unroll
  for (int kc = 0; kc < 4; ++kc) {
    size_t aidx = ((size_t)bq * NA + a0 + w * 16 + l15) * MDIM + kc * 32 + l4 * 8;
    aH[kc] = *(const short8*)(maH + aidx);
    aM[kc] = *(const short8*)(maM + aidx);
  }

  const unsigned short* bplane = (w >> 1) ? mbM : mbH;
  const char* sp0; const char* sp1; const char* sp2; const char* sp3;
  {
    const int clb = (w & 1) * 16 + l4;
    const size_t rowb = (size_t)bq * NA + cs * 512;
    sp0 = (const char*)bplane + ((rowb + clb +  0) << 8) + ((l15 ^ ((clb +  0) & 7)) << 4);
    sp1 = (const char*)bplane + ((rowb + clb +  4) << 8) + ((l15 ^ ((clb +  4) & 7)) << 4);
    sp2 = (const char*)bplane + ((rowb + clb +  8) << 8) + ((l15 ^ ((clb +  8) & 7)) << 4);
    sp3 = (const char*)bplane + ((rowb + clb + 12) << 8) + ((l15 ^ ((clb + 12) & 7)) << 4);
  }

  float bv1[4], bv2[4];
  int bi1[4];
#pragma unroll
  for (int s = 0; s < 4; ++s) { bv1[s] = -1e30f; bv2[s] = -1e30f; bi1[s] = 0x7FFFFFFF; }

  auto stage = [&](int bufn) {
    char* dst = (char*)&lds8[bufn][0][0][0] + w * 4096 + l * 16;
    __builtin_amdgcn_global_load_lds((const __attribute__((address_space(1))) void*)sp0,
        (__attribute__((address_space(3))) void*)(dst + 0),    16, 0, 0);
    __builtin_amdgcn_global_load_lds((const __attribute__((address_space(1))) void*)sp1,
        (__attribute__((address_space(3))) void*)(dst + 1024), 16, 0, 0);
    __builtin_amdgcn_global_load_lds((const __attribute__((address_space(1))) void*)sp2,
        (__attribute__((address_space(3))) void*)(dst + 2048), 16, 0, 0);
    __builtin_amdgcn_global_load_lds((const __attribute__((address_space(1))) void*)sp3,
        (__attribute__((address_space(3))) void*)(dst + 3072), 16, 0, 0);
    sp0 += 8192; sp1 += 8192; sp2 += 8192; sp3 += 8192;
  };

  auto compute = [&](int bufn, int cbase) {
    f32x4 acc1[2], acc2[2];
    acc1[0] = 0.f; acc1[1] = 0.f; acc2[0] = 0.f; acc2[1] = 0.f;
#pragma unroll
    for (int kc = 0; kc < 4; ++kc) {
      const int gg = (kc * 4 + l4) ^ l7;
#pragma unroll
      for (int cf = 0; cf < 2; ++cf) {
        short8 bh = lds8[bufn][0][cf * 16 + l15][gg];
        short8 bm = lds8[bufn][1][cf * 16 + l15][gg];
        acc1[cf] = __builtin_amdgcn_mfma_f32_16x16x32_bf16(aH[kc], bh, acc1[cf], 0, 0, 0);
        acc2[cf] = __builtin_amdgcn_mfma_f32_16x16x32_bf16(aH[kc], bm, acc2[cf], 0, 0, 0);
        acc2[cf] = __builtin_amdgcn_mfma_f32_16x16x32_bf16(aM[kc], bh, acc2[cf], 0, 0, 0);
      }
    }
#pragma unroll
    for (int cf = 0; cf < 2; ++cf) {
      const int cg = cbase + cf * 16 + l15;
      f32x4 v4 = acc1[cf] + acc2[cf];
#pragma unroll
      for (int r2 = 0; r2 < 4; ++r2) {
        float v = v4[r2];
        if (v > bv1[r2]) { bv2[r2] = bv1[r2]; bv1[r2] = v; bi1[r2] = cg; }
        else if (v > bv2[r2]) bv2[r2] = v;
      }
    }
  };

  stage(0);
  __syncthreads();
  const int cb0 = cs * 512;
  for (int chp = 0; chp < 8; ++chp) {
    const int ch = chp * 2;
    if (ch + 1 < 16) stage(1);
    compute(0, cb0 + ch * 32);
    __syncthreads();
    if (ch + 2 < 16) stage(0);
    compute(1, cb0 + ch * 32 + 32);
    __syncthreads();
  }

#pragma unroll
  for (int s = 0; s < 4; ++s) {
    float v1 = bv1[s], v2 = bv2[s];
    int i1 = bi1[s];
#pragma unroll
    for (int m = 1; m < 16; m <<= 1) {
      float V1 = __shfl_xor(v1, m);
      int I1 = __shfl_xor(i1, m);
      float V2 = __shfl_xor(v2, m);
      bool take = (V1 > v1) || (V1 == v1 && I1 < i1);
      float lose = take ? v1 : V1;
      if (take) { v1 = V1; i1 = I1; }
      v2 = fmaxf(fmaxf(v2, V2), lose);
    }
    if (l15 == s) {
      int row = a0 + w * 16 + l4 * 4 + s;
      size_t off = ((size_t)(bq * CSPL + cs)) * NA + row;
      pv1[off] = v1; pi1[off] = i1; pv2[off] = v2;
    }
  }
}

// ---------------------------------------------------------------------------
// K3 (fused): merge 8 csplit partials + init cnt/head/rescueKey/rescueCnt +
// radix rank-select -> rank-2048 value vb + mark rescue rows. (validated)
// ---------------------------------------------------------------------------
__global__ __launch_bounds__(1024) void k_mergemark(
    const float* __restrict__ pv1, const int* __restrict__ pi1,
    const float* __restrict__ pv2,
    float* __restrict__ valA, int* __restrict__ nodeA,
    int* __restrict__ rescueCnt, int* __restrict__ rescueIdx,
    int* __restrict__ cnt, int* __restrict__ head,
    unsigned long long* __restrict__ rescueKey) {
  __shared__ unsigned long long keys[NA];
  __shared__ unsigned hist[NA];
  __shared__ unsigned long long cand[1024];
  __shared__ unsigned scan1[1024];
  __shared__ unsigned shw[4];
  const int b = blockIdx.x, t = threadIdx.x;
  if (t == 0) rescueCnt[b] = 0;
  float gval[4], ggap[4];
#pragma unroll
  for (int k4 = 0; k4 < 4; ++k4) {
    const int p = t + k4 * 1024;
    const size_t i = (size_t)b * NA + p;
    float v1 = -1e30f, v2 = -1e30f;
    int i1 = 0x7FFFFFFF;
#pragma unroll
    for (int cspl = 0; cspl < CSPL; ++cspl) {
      size_t o = ((size_t)(b * CSPL + cspl)) * NA + p;
      float V1 = pv1[o], V2 = pv2[o];
      int I1 = pi1[o];
      bool take = (V1 > v1) || (V1 == v1 && I1 < i1);
      float lose = take ? v1 : V1;
      if (take) { v1 = V1; i1 = I1; }
      v2 = fmaxf(fmaxf(v2, V2), lose);
    }
    valA[i] = v1; nodeA[i] = i1;
    cnt[i] = 0; head[i] = -1; rescueKey[i] = 0ull;
    gval[k4] = v1; ggap[k4] = v1 - v2;
    unsigned u = __float_as_uint(v1);
    unsigned mono = u ^ ((u >> 31) ? 0xFFFFFFFFu : 0x80000000u);
    keys[p] = ((unsigned long long)(~mono) << 32) | (unsigned)p;
  }
  __syncthreads();

  const unsigned long long thr =
      rank_select_4096(keys, hist, cand, scan1, shw, RSEL - 1, t);
  unsigned monoT = ~(unsigned)(thr >> 32);
  unsigned uT = (monoT >> 31) ? (monoT ^ 0x80000000u) : ~monoT;
  const float vb = __uint_as_float(uT);

#pragma unroll
  for (int k4 = 0; k4 < 4; ++k4) {
    const int p = t + k4 * 1024;
    if (ggap[k4] < GAP_DELTA || fabsf(gval[k4] - vb) <= WIN_TAU) {
      int slot = atomicAdd(&rescueCnt[b], 1);
      if (slot < RESCUE_CAP) rescueIdx[b * RESCUE_CAP + slot] = p;
    }
  }
}

// ---------------------------------------------------------------------------
// K4: exact fp32 recompute, parallel over (slot x 16 column-chunks).
// (validated, unchanged)
// ---------------------------------------------------------------------------
__global__ __launch_bounds__(256) void k_rescue(const float* __restrict__ ma,
                                                const float* __restrict__ mb,
                                                const int* __restrict__ rescueIdx,
                                                const int* __restrict__ rescueCnt,
                                                unsigned long long* __restrict__ key) {
  const int bq = blockIdx.x >> 8;
  const int wid = blockIdx.x & 255;
  const int cnt = min(rescueCnt[bq], RESCUE_CAP);
  const int npair = cnt * 16;
  const int t = threadIdx.x;
  __shared__ float sA[128];
  __shared__ float wv[4];
  __shared__ int   wi[4];
  for (int pair = wid; pair < npair; pair += 256) {
    const int slot = pair >> 4, chunk = pair & 15;
    const int row = rescueIdx[bq * RESCUE_CAP + slot];
    __syncthreads();
    if (t < 128) sA[t] = ma[((size_t)bq * NA + row) * MDIM + t];
    __syncthreads();
    const int c = chunk * 256 + t;
    const float* bp = mb + ((size_t)bq * NA + c) * MDIM;
    float d0 = 0.f, d1 = 0.f, d2 = 0.f, d3 = 0.f;
#pragma unroll
    for (int j = 0; j < 8; ++j) {
      float4 b0 = *(const float4*)(bp + j * 16 + 0);
      float4 b1 = *(const float4*)(bp + j * 16 + 4);
      float4 b2 = *(const float4*)(bp + j * 16 + 8);
      float4 b3 = *(const float4*)(bp + j * 16 + 12);
      const float4 a0 = *(const float4*)&sA[j * 16 + 0];
      const float4 a1 = *(const float4*)&sA[j * 16 + 4];
      const float4 a2 = *(const float4*)&sA[j * 16 + 8];
      const float4 a3 = *(const float4*)&sA[j * 16 + 12];
      d0 = fmaf(a0.x, b0.x, d0); d0 = fmaf(a0.y, b0.y, d0);
      d0 = fmaf(a0.z, b0.z, d0); d0 = fmaf(a0.w, b0.w, d0);
      d1 = fmaf(a1.x, b1.x, d1); d1 = fmaf(a1.y, b1.y, d1);
      d1 = fmaf(a1.z, b1.z, d1); d1 = fmaf(a1.w, b1.w, d1);
      d2 = fmaf(a2.x, b2.x, d2); d2 = fmaf(a2.y, b2.y, d2);
      d2 = fmaf(a2.z, b2.z, d2); d2 = fmaf(a2.w, b2.w, d2);
      d3 = fmaf(a3.x, b3.x, d3); d3 = fmaf(a3.y, b3.y, d3);
      d3 = fmaf(a3.z, b3.z, d3); d3 = fmaf(a3.w, b3.w, d3);
    }
    float d = (d0 + d1) + (d2 + d3);
    int ci = c;
#pragma unroll
    for (int m = 1; m < 64; m <<= 1) {
      float V = __shfl_xor(d, m);
      int C = __shfl_xor(ci, m);
      if (V > d || (V == d && C < ci)) { d = V; ci = C; }
    }
    if ((t & 63) == 0) { wv[t >> 6] = d; wi[t >> 6] = ci; }
    __syncthreads();
    if (t == 0) {
      for (int w2 = 1; w2 < 4; ++w2)
        if (wv[w2] > d || (wv[w2] == d && wi[w2] < ci)) { d = wv[w2]; ci = wi[w2]; }
      unsigned u = __float_as_uint(d);
      unsigned mono = u ^ ((u >> 31) ? 0xFFFFFFFFu : 0x80000000u);
      unsigned long long k = ((unsigned long long)mono << 32)
                           | (unsigned)(0xFFFFFFFFu - (unsigned)ci);
      atomicMax(&key[(size_t)bq * NA + row], k);
    }
  }
}

// ---------------------------------------------------------------------------
// K5 (fused): decode rescued keys + EXACT top-2048 via radix rank-select +
// build merge lists + mask scan -> newidx + ownership. (validated)
// ---------------------------------------------------------------------------
__global__ __launch_bounds__(1024) void k_select(
    const unsigned long long* __restrict__ rescueKey,
    const float* __restrict__ valA, const int* __restrict__ nodeA,
    int* __restrict__ sel, int* __restrict__ cnt, int* __restrict__ head,
    int* __restrict__ nxt, int* __restrict__ newidx,
    float* __restrict__ own) {
  __shared__ unsigned long long keys[NA];
  __shared__ int nodeL[NA];
  __shared__ unsigned char selL[NA];
  __shared__ int ni[NTOK];
  __shared__ unsigned tot[1024];
  __shared__ unsigned hist[NA];
  __shared__ unsigned long long cand[1024];
  __shared__ unsigned shw[4];
  const int b = blockIdx.x, t = threadIdx.x;

#pragma unroll
  for (int k4 = 0; k4 < 4; ++k4) {
    const int p = t + k4 * 1024;
    const size_t i = (size_t)b * NA + p;
    unsigned long long rk = rescueKey[i];
    float v; int nd;
    if (rk) {
      unsigned mono = (unsigned)(rk >> 32);
      unsigned u = (mono & 0x80000000u) ? (mono ^ 0x80000000u) : ~mono;
      v = __uint_as_float(u);
      nd = (int)(0xFFFFFFFFu - (unsigned)(rk & 0xFFFFFFFFull));
    } else {
      v = valA[i];
      nd = nodeA[i];
    }
    nodeL[p] = nd;
    unsigned u = __float_as_uint(v);
    unsigned mono = u ^ ((u >> 31) ? 0xFFFFFFFFu : 0x80000000u);
    keys[p] = ((unsigned long long)(~mono) << 32) | (unsigned)p;
  }
  __syncthreads();

  const unsigned long long thr =
      rank_select_4096(keys, hist, cand, tot, shw, RSEL - 1, t);

#pragma unroll
  for (int k4 = 0; k4 < 4; ++k4) {
    const int p = t + k4 * 1024;
    selL[p] = (keys[p] <= thr) ? 1 : 0;
  }
  __syncthreads();

#pragma unroll
  for (int k4 = 0; k4 < 4; ++k4) {
    const int p = t + k4 * 1024;
    const size_t i = (size_t)b * NA + p;
    int s = selL[p];
    sel[i] = s;
    if (s) {
      int dst = nodeL[p];
      atomicAdd(&cnt[(size_t)b * NA + dst], 1);
      nxt[i] = atomicExch(&head[(size_t)b * NA + dst], p);
    }
  }

  const int base = t * 8;
  int kept[8], run = 0;
#pragma unroll
  for (int e = 0; e < 8; ++e) {
    int idx = base + e;
    int kp = ((idx & 1) == 0) ? 1 : (selL[idx >> 1] ? 0 : 1);
    kept[e] = kp;
    run += kp;
  }
  tot[t] = (unsigned)run;
  __syncthreads();
  for (int off = 1; off < 1024; off <<= 1) {
    unsigned v = (t >= off) ? tot[t - off] : 0;
    __syncthreads();
    tot[t] += v;
    __syncthreads();
  }
  int cum = (int)tot[t] - run;
#pragma unroll
  for (int e = 0; e < 8; ++e) {
    cum += kept[e];
    ni[base + e] = cum - 1;
  }
  __syncthreads();
#pragma unroll
  for (int e = 0; e < 8; ++e) {
    int idx = base + e;
    int ow = kept[e] ? ni[idx] : ni[2 * nodeL[idx >> 1]];
    newidx[(size_t)b * NTOK + idx] = ni[idx];
    own[(size_t)b * NTOK + idx] = (float)ow;
  }
}

// ---------------------------------------------------------------------------
// K6: assemble x_final f32 (gather merges via linked list, divide, compact).
// 2 tokens per 256-thread block. (validated, unchanged)
// ---------------------------------------------------------------------------
__global__ __launch_bounds__(256) void k_assemble(const float* __restrict__ X,
                                                  const int* __restrict__ sel,
                                                  const int* __restrict__ newidx,
                                                  const int* __restrict__ cnt,
                                                  const int* __restrict__ head,
                                                  const int* __restrict__ nxt,
                                                  float* __restrict__ out) {
  const int token = blockIdx.x * 2 + (threadIdx.x >> 7);
  const int bq = token >> 13, tp = token & (NTOK - 1);
  const int t = threadIdx.x & 127;
  if ((tp & 1) && sel[(size_t)bq * NA + (tp >> 1)]) return;
  float4 v = *(const float4*)(X + (size_t)token * CDIM + t * 4);
  if (!(tp & 1)) {
    size_t slot = (size_t)bq * NA + (tp >> 1);
    int c = cnt[slot];
    if (c > 0) {
      int kk = head[slot];
      while (kk >= 0) {
        float4 s = *(const float4*)(X + ((size_t)bq * NTOK + 2 * kk + 1) * CDIM + t * 4);
        v.x += s.x; v.y += s.y; v.z += s.z; v.w += s.w;
        kk = nxt[(size_t)bq * NA + kk];
      }
      float inv = 1.0f / (float)(1 + c);
      v.x *= inv; v.y *= inv; v.z *= inv; v.w *= inv;
    }
  }
  int dst = newidx[(size_t)bq * NTOK + tp];
  *(float4*)(out + ((size_t)bq * NKEEP + dst) * CDIM + t * 4) = v;
}

// ---------------------------------------------------------------------------
extern "C" void kernel_launch(void* const* d_in, const int* in_sizes, int n_in,
                              void* d_out, int out_size, void* d_ws, size_t ws_size,
                              hipStream_t stream) {
  const float* X    = (const float*)d_in[0];
  const float* W    = (const float*)d_in[1];
  const float* bias = (const float*)d_in[2];
  float* out = (float*)d_out;  // f32: x_final (4,6144,512) ++ ownership (4,8192)
  char* ws = (char*)d_ws;

  size_t o = 0;
  float* ma   = (float*)(ws + o); o += (size_t)BQ * NA * MDIM * 4;
  float* mb   = (float*)(ws + o); o += (size_t)BQ * NA * MDIM * 4;
  unsigned short* maH = (unsigned short*)(ws + o); o += (size_t)BQ * NA * MDIM * 2;
  unsigned short* maM = (unsigned short*)(ws + o); o += (size_t)BQ * NA * MDIM * 2;
  unsigned short* mbH = (unsigned short*)(ws + o); o += (size_t)BQ * NA * MDIM * 2;
  unsigned short* mbM = (unsigned short*)(ws + o); o += (size_t)BQ * NA * MDIM * 2;
  float* pv1  = (float*)(ws + o); o += (size_t)BQ * CSPL * NA * 4;
  int*   pi1  = (int*)(ws + o);   o += (size_t)BQ * CSPL * NA * 4;
  float* pv2  = (float*)(ws + o); o += (size_t)BQ * CSPL * NA * 4;
  float* valA = (float*)(ws + o); o += (size_t)BQ * NA * 4;
  int*   nodeA= (int*)(ws + o);   o += (size_t)BQ * NA * 4;
  int*   sel  = (int*)(ws + o);   o += (size_t)BQ * NA * 4;
  int*   cnt  = (int*)(ws + o);   o += (size_t)BQ * NA * 4;
  int*   head = (int*)(ws + o);   o += (size_t)BQ * NA * 4;
  int*   nxt  = (int*)(ws + o);   o += (size_t)BQ * NA * 4;
  int*   newidx = (int*)(ws + o); o += (size_t)BQ * NTOK * 4;
  int*   rescueCnt = (int*)(ws + o); o += 256;
  int*   rescueIdx = (int*)(ws + o); o += (size_t)BQ * RESCUE_CAP * 4;
  unsigned long long* rescueKey = (unsigned long long*)(ws + o); o += (size_t)BQ * NA * 8;
  (void)in_sizes; (void)n_in; (void)out_size; (void)ws_size;

  k_metric<<<512, 128, 0, stream>>>(X, W, bias, ma, mb, maH, maM, mbH, mbM);
  k_scores_mfma<<<BQ * 64 * CSPL, 256, 0, stream>>>(maH, maM, mbH, mbM, pv1, pi1, pv2);
  k_mergemark<<<BQ, 1024, 0, stream>>>(pv1, pi1, pv2, valA, nodeA,
                                       rescueCnt, rescueIdx, cnt, head, rescueKey);
  k_rescue<<<BQ * 256, 256, 0, stream>>>(ma, mb, rescueIdx, rescueCnt, rescueKey);
  k_select<<<BQ, 1024, 0, stream>>>(rescueKey, valA, nodeA, sel, cnt, head, nxt,
                                    newidx, out + (size_t)BQ * NKEEP * CDIM);
  k_assemble<<<BQ * NTOK / 2, 256, 0, stream>>>(X, sel, newidx, cnt, head, nxt, out);
}